// Round 2
// baseline (1073.398 us; speedup 1.0000x reference)
//
#include <hip/hip_runtime.h>
#include <stdint.h>

#define BB 2
#define NQ 900
#define NKtot 10000
#define CH 256
#define NH 8
#define DH 32
#define NQ_PAD 912
#define NK_PAD 10048
#define ATT_SCALE 0.1767766952966369f  // 32^-0.5

typedef __attribute__((ext_vector_type(8))) short bf16x8;
typedef __attribute__((ext_vector_type(4))) short bf16x4;
typedef __attribute__((ext_vector_type(4))) float f32x4;

__device__ __forceinline__ unsigned short f2bf(float f) {
  unsigned u = __float_as_uint(f);
  u = (u + 0x7FFFu + ((u >> 16) & 1u)) >> 16;
  return (unsigned short)u;
}

// ---- one-shot: transpose+convert the four 256x256 fp32 W into bf16 W^T [col][k] ----
__launch_bounds__(256)
__global__ void wtrans_kernel(const float* __restrict__ W0, const float* __restrict__ W1,
                              const float* __restrict__ W2, const float* __restrict__ W3,
                              unsigned short* __restrict__ Wt)
{
  __shared__ unsigned short lds[64][72];
  const int mat = blockIdx.x >> 4, tile = blockIdx.x & 15;
  const int k0 = (tile >> 2) * 64, c0 = (tile & 3) * 64;
  const float* W = mat == 0 ? W0 : mat == 1 ? W1 : mat == 2 ? W2 : W3;
  const int t = threadIdx.x;
  const int r = t >> 4, cg = t & 15;
#pragma unroll
  for (int rr = 0; rr < 4; ++rr) {
    const int row = r + rr * 16;
    float4 f = *(const float4*)(W + (size_t)(k0 + row) * 256 + c0 + cg * 4);
    union { unsigned short s[4]; bf16x4 v; } pk;
    pk.s[0] = f2bf(f.x); pk.s[1] = f2bf(f.y); pk.s[2] = f2bf(f.z); pk.s[3] = f2bf(f.w);
    *(bf16x4*)&lds[row][cg * 4] = pk.v;
  }
  __syncthreads();
  const int c = t >> 2, kq = (t & 3) * 16;
  union { unsigned short s[16]; bf16x8 v[2]; } o;
#pragma unroll
  for (int j = 0; j < 16; ++j) o.s[j] = lds[kq + j][c];
  unsigned short* dst = Wt + (size_t)mat * 65536 + (size_t)(c0 + c) * 256 + k0 + kq;
  *(bf16x8*)dst = o.v[0];
  *(bf16x8*)(dst + 8) = o.v[1];
}

// ---- zero pad regions (poisoned 0xAA = NaN bf16 would leak via PV NaN*0) + maskf ----
__global__ void pad_zero(unsigned short* __restrict__ Qw, unsigned short* __restrict__ Kw,
                         unsigned short* __restrict__ Vt, float* __restrict__ maskf,
                         const int* __restrict__ kmask)
{
  const int i = blockIdx.x * 256 + threadIdx.x;   // grid 96*256 = 24576
  if (i < 16 * 48 * 32) {           // Kw pad rows
    int bh = i / (48 * 32), rem = i % (48 * 32);
    int n = NKtot + rem / 32, d = rem % 32;
    Kw[((size_t)bh * NK_PAD + n) * DH + d] = 0;
  }
  if (i < 16 * 32 * 48) {           // Vt pad cols
    int bh = i / (32 * 48), rem = i % (32 * 48);
    int d = rem / 48, n = NKtot + rem % 48;
    Vt[((size_t)bh * DH + d) * NK_PAD + n] = 0;
  }
  if (i < 16 * 12 * 32) {           // Qw pad rows
    int bh = i / (12 * 32), rem = i % (12 * 32);
    int q = NQ + rem / 32, d = rem % 32;
    Qw[((size_t)bh * NQ_PAD + q) * DH + d] = 0;
  }
  if (i < 2 * NK_PAD) {             // maskf = -100*mask, -1e30 beyond NKtot
    int b = i / NK_PAD, n = i % NK_PAD;
    maskf[i] = (n < NKtot) ? -100.f * (float)kmask[b * NKtot + n] : -1e30f;
  }
}

// ---- projection GEMM: out = X[rows,256] @ W + bias (+pos); W^T bf16 from global ----
// mode 0: Q*SCALE -> bf16 [B,H,NQ_PAD,32]; 1: K -> [B,H,NK_PAD,32];
// 2: V -> V^T [B,H,32,NK_PAD]; 3: fp32 [rows,256]
__launch_bounds__(256)
__global__ void proj_kernel(const float* __restrict__ X, const unsigned short* __restrict__ Wt,
                            const float* __restrict__ bias, const float* __restrict__ pos,
                            void* __restrict__ out, int rows, int Nper, int mode)
{
  __shared__ unsigned short Alds[64 * 40];
  const int t = threadIdx.x;
  const int w = t >> 6, l = t & 63, g = l >> 4, q16 = l & 15;
  const int r0 = blockIdx.x * 64;
  const int c0 = w * 64;

  f32x4 acc[4][4];
#pragma unroll
  for (int i = 0; i < 4; ++i)
#pragma unroll
    for (int j = 0; j < 4; ++j) acc[i][j] = f32x4{0.f, 0.f, 0.f, 0.f};

  for (int ks = 0; ks < 8; ++ks) {
    const int kc = ks * 32;
    __syncthreads();
    { // stage A tile (64 rows x 32 k) -> bf16, one 16B LDS write per thread
      int row = t >> 2, koff = (t & 3) * 8;
      int grow = r0 + row;
      float4 f0 = {0.f,0.f,0.f,0.f}, f1 = {0.f,0.f,0.f,0.f};
      if (grow < rows) {
        const float* p = X + (size_t)grow * CH + kc + koff;
        f0 = *(const float4*)p;
        f1 = *(const float4*)(p + 4);
      }
      union { unsigned short s[8]; bf16x8 v; } pk;
      pk.s[0]=f2bf(f0.x); pk.s[1]=f2bf(f0.y); pk.s[2]=f2bf(f0.z); pk.s[3]=f2bf(f0.w);
      pk.s[4]=f2bf(f1.x); pk.s[5]=f2bf(f1.y); pk.s[6]=f2bf(f1.z); pk.s[7]=f2bf(f1.w);
      *(bf16x8*)&Alds[row * 40 + koff] = pk.v;
    }
    __syncthreads();
    bf16x8 af[4], bfr[4];
#pragma unroll
    for (int ct = 0; ct < 4; ++ct)
      bfr[ct] = *(const bf16x8*)(Wt + (size_t)(c0 + ct * 16 + q16) * 256 + kc + g * 8);
#pragma unroll
    for (int mt = 0; mt < 4; ++mt)
      af[mt] = *(const bf16x8*)&Alds[(mt * 16 + q16) * 40 + g * 8];
#pragma unroll
    for (int mt = 0; mt < 4; ++mt)
#pragma unroll
      for (int ct = 0; ct < 4; ++ct)
        acc[mt][ct] = __builtin_amdgcn_mfma_f32_16x16x32_bf16(af[mt], bfr[ct], acc[mt][ct], 0, 0, 0);
  }

#pragma unroll
  for (int mt = 0; mt < 4; ++mt)
#pragma unroll
    for (int ct = 0; ct < 4; ++ct) {
      const int col = c0 + ct * 16 + q16;
      const float bv = bias[col];
#pragma unroll
      for (int r = 0; r < 4; ++r) {
        int grow = r0 + mt * 16 + g * 4 + r;
        if (grow >= rows) continue;
        float v = acc[mt][ct][r] + bv;
        if (pos) v += pos[(size_t)grow * CH + col];
        if (mode == 3) {
          ((float*)out)[(size_t)grow * CH + col] = v;
        } else {
          int b = grow / Nper, n = grow - b * Nper;
          int h = col >> 5, d = col & 31;
          if (mode == 0) v *= ATT_SCALE;   // fold score scale into Q
          unsigned short bv16 = f2bf(v);
          if (mode == 2)
            ((unsigned short*)out)[((size_t)(b * NH + h) * DH + d) * NK_PAD + n] = bv16;
          else {
            int npad = (mode == 0) ? NQ_PAD : NK_PAD;
            ((unsigned short*)out)[((size_t)(b * NH + h) * npad + n) * DH + d] = bv16;
          }
        }
      }
    }
}

// ---- flash attention: S^T = mfma(K,Q); online softmax per lane-col; O^T = mfma(V^T,P^T) ----
__launch_bounds__(256)
__global__ void attn_kernel(const unsigned short* __restrict__ Qw,
                            const unsigned short* __restrict__ Kw,
                            const unsigned short* __restrict__ Vt,
                            const float* __restrict__ rpe,
                            const float* __restrict__ maskf,
                            float* __restrict__ xout)
{
  const int NT = 57;
  const int lb = blockIdx.x;
  const int bid = (lb & 7) * 114 + (lb >> 3);   // XCD swizzle: 912 = 8*114, bijective
  const int bh = bid / NT;
  const int qt = bid - bh * NT;
  const int b = bh >> 3, h = bh & 7;
  const int t = threadIdx.x;
  const int w = t >> 6, l = t & 63, g = l >> 4, q16 = l & 15;
  const int q0 = qt * 16;
  const int q = q0 + q16;
  const bool qok = q < NQ;

  const bf16x8 qf = *(const bf16x8*)(Qw + ((size_t)bh * NQ_PAD + q) * DH + g * 8);
  const unsigned short* Kbh = Kw + (size_t)bh * NK_PAD * DH;
  const unsigned short* Vbh = Vt + (size_t)bh * DH * NK_PAD;
  const float* rpeq = rpe + ((size_t)bh * NQ + q) * NKtot;
  const float* mfb = maskf + (size_t)b * NK_PAD;

  const int kstart = w * 2496;
  const int niter = (w == 3) ? 79 : 78;

  float m = -INFINITY, lsum = 0.f;
  f32x4 acc0 = {0.f,0.f,0.f,0.f}, acc1 = {0.f,0.f,0.f,0.f};
  const f32x4 zero4 = {0.f,0.f,0.f,0.f};

  for (int it = 0; it < niter; ++it) {
    const int kt = kstart + it * 32;
    bf16x8 kf0 = *(const bf16x8*)(Kbh + (size_t)(kt + q16) * DH + g * 8);
    bf16x8 kf1 = *(const bf16x8*)(Kbh + (size_t)(kt + 16 + q16) * DH + g * 8);
    f32x4 st0 = __builtin_amdgcn_mfma_f32_16x16x32_bf16(kf0, qf, zero4, 0, 0, 0);
    f32x4 st1 = __builtin_amdgcn_mfma_f32_16x16x32_bf16(kf1, qf, zero4, 0, 0, 0);

    const int key40 = kt + g * 4;
    const int key41 = key40 + 16;
    f32x4 mf0 = *(const f32x4*)(mfb + key40);       // -100*mask, -1e30 in pad
    f32x4 mf1 = *(const f32x4*)(mfb + key41);
    f32x4 r0v = {0.f,0.f,0.f,0.f}, r1v = {0.f,0.f,0.f,0.f};
    if (qok && key40 < NKtot) r0v = __builtin_nontemporal_load((const f32x4*)(rpeq + key40));
    if (qok && key41 < NKtot) r1v = __builtin_nontemporal_load((const f32x4*)(rpeq + key41));

    float s0 = st0[0] + r0v[0] + mf0[0];
    float s1 = st0[1] + r0v[1] + mf0[1];
    float s2 = st0[2] + r0v[2] + mf0[2];
    float s3 = st0[3] + r0v[3] + mf0[3];
    float s4 = st1[0] + r1v[0] + mf1[0];
    float s5 = st1[1] + r1v[1] + mf1[1];
    float s6 = st1[2] + r1v[2] + mf1[2];
    float s7 = st1[3] + r1v[3] + mf1[3];

    float pmax = fmaxf(fmaxf(fmaxf(s0,s1),fmaxf(s2,s3)), fmaxf(fmaxf(s4,s5),fmaxf(s6,s7)));
    pmax = fmaxf(pmax, __shfl_xor(pmax, 16));
    pmax = fmaxf(pmax, __shfl_xor(pmax, 32));
    const float mnew = fmaxf(m, pmax);
    const float alpha = __expf(m - mnew);
    m = mnew;
    float p0 = __expf(s0 - mnew), p1 = __expf(s1 - mnew);
    float p2 = __expf(s2 - mnew), p3 = __expf(s3 - mnew);
    float p4 = __expf(s4 - mnew), p5 = __expf(s5 - mnew);
    float p6 = __expf(s6 - mnew), p7 = __expf(s7 - mnew);
    lsum = lsum * alpha + (p0+p1+p2+p3) + (p4+p5+p6+p7);
#pragma unroll
    for (int i = 0; i < 4; ++i) { acc0[i] *= alpha; acc1[i] *= alpha; }

    // pack P (C/D layout keys kt+16t+4g'+r) -> B-frag layout (keys kt+8g+e)
    unsigned pk00 = (unsigned)f2bf(p0) | ((unsigned)f2bf(p1) << 16);
    unsigned pk01 = (unsigned)f2bf(p2) | ((unsigned)f2bf(p3) << 16);
    unsigned pk10 = (unsigned)f2bf(p4) | ((unsigned)f2bf(p5) << 16);
    unsigned pk11 = (unsigned)f2bf(p6) | ((unsigned)f2bf(p7) << 16);
    const int srcLo = (((2*g) & 3) << 4) | q16;
    const int srcHi = (((2*g + 1) & 3) << 4) | q16;
    const bool tn = g >= 2;
    unsigned a0 = (unsigned)__shfl((int)pk00, srcLo);
    unsigned a1 = (unsigned)__shfl((int)pk01, srcLo);
    unsigned b0 = (unsigned)__shfl((int)pk10, srcLo);
    unsigned b1 = (unsigned)__shfl((int)pk11, srcLo);
    unsigned c0u = (unsigned)__shfl((int)pk00, srcHi);
    unsigned c1u = (unsigned)__shfl((int)pk01, srcHi);
    unsigned d0u = (unsigned)__shfl((int)pk10, srcHi);
    unsigned d1u = (unsigned)__shfl((int)pk11, srcHi);
    union { unsigned u[4]; bf16x8 v; } pb;
    pb.u[0] = tn ? b0 : a0;
    pb.u[1] = tn ? b1 : a1;
    pb.u[2] = tn ? d0u : c0u;
    pb.u[3] = tn ? d1u : c1u;

    bf16x8 vf0 = *(const bf16x8*)(Vbh + (size_t)q16 * NK_PAD + kt + g * 8);
    bf16x8 vf1 = *(const bf16x8*)(Vbh + (size_t)(16 + q16) * NK_PAD + kt + g * 8);
    acc0 = __builtin_amdgcn_mfma_f32_16x16x32_bf16(vf0, pb.v, acc0, 0, 0, 0);
    acc1 = __builtin_amdgcn_mfma_f32_16x16x32_bf16(vf1, pb.v, acc1, 0, 0, 0);
  }

  lsum += __shfl_xor(lsum, 16);
  lsum += __shfl_xor(lsum, 32);

  __shared__ float smm[4][16], sml[4][16], smacc[4][32][16];
  if (l < 16) { smm[w][l] = m; sml[w][l] = lsum; }
#pragma unroll
  for (int r = 0; r < 4; ++r) {
    smacc[w][g*4 + r][q16] = acc0[r];
    smacc[w][16 + g*4 + r][q16] = acc1[r];
  }
  __syncthreads();
#pragma unroll
  for (int ii = 0; ii < 2; ++ii) {
    int e = t + ii * 256;
    int d = e >> 4, qq = e & 15;
    float M = fmaxf(fmaxf(smm[0][qq], smm[1][qq]), fmaxf(smm[2][qq], smm[3][qq]));
    float den = 0.f, num = 0.f;
#pragma unroll
    for (int ww = 0; ww < 4; ++ww) {
      float al = __expf(smm[ww][qq] - M);
      den += al * sml[ww][qq];
      num += al * smacc[ww][d][qq];
    }
    if (q0 + qq < NQ)
      xout[((size_t)b * NQ + q0 + qq) * CH + h * DH + d] = num / den;
  }
}

extern "C" void kernel_launch(void* const* d_in, const int* in_sizes, int n_in,
                              void* d_out, int out_size, void* d_ws, size_t ws_size,
                              hipStream_t stream)
{
  const float* query = (const float*)d_in[0];
  const float* key   = (const float*)d_in[1];
  const float* value = (const float*)d_in[2];
  const float* rpe   = (const float*)d_in[3];
  // d_in[4] spatial_shapes unused
  const int*   kmask = (const int*)d_in[5];
  const float* qpos  = (const float*)d_in[6];
  const float* kpos  = (const float*)d_in[7];
  const float* Wq = (const float*)d_in[8];  const float* bq = (const float*)d_in[9];
  const float* Wk = (const float*)d_in[10]; const float* bk = (const float*)d_in[11];
  const float* Wv = (const float*)d_in[12]; const float* bv = (const float*)d_in[13];
  const float* Wp = (const float*)d_in[14]; const float* bp = (const float*)d_in[15];

  char* ws = (char*)d_ws;
  size_t off = 0;
  unsigned short* Qw = (unsigned short*)(ws + off); off += (size_t)16 * NQ_PAD * DH * 2;  // 933,888
  unsigned short* Kw = (unsigned short*)(ws + off); off += (size_t)16 * NK_PAD * DH * 2;  // 10,289,152
  unsigned short* Vt = (unsigned short*)(ws + off); off += (size_t)16 * DH * NK_PAD * 2;  // 10,289,152
  float* maskf = (float*)(ws + off);               off += (size_t)BB * NK_PAD * 4;        // 80,384
  float* xws = (float*)(ws + off);                 off += (size_t)BB * NQ * CH * 4;       // 1,843,200
  unsigned short* Wt = (unsigned short*)(ws + off);                                       // 524,288

  wtrans_kernel<<<64, 256, 0, stream>>>(Wq, Wk, Wv, Wp, Wt);
  pad_zero<<<96, 256, 0, stream>>>(Qw, Kw, Vt, maskf, kmask);
  proj_kernel<<<29,  256, 0, stream>>>(query, Wt,            bq, qpos,    (void*)Qw, BB*NQ,    NQ,    0);
  proj_kernel<<<313, 256, 0, stream>>>(key,   Wt + 65536,    bk, kpos,    (void*)Kw, BB*NKtot, NKtot, 1);
  proj_kernel<<<313, 256, 0, stream>>>(value, Wt + 2*65536,  bv, nullptr, (void*)Vt, BB*NKtot, NKtot, 2);
  attn_kernel<<<912, 256, 0, stream>>>(Qw, Kw, Vt, rpe, maskf, xws);
  proj_kernel<<<29,  256, 0, stream>>>(xws, Wt + 3*65536,    bp, nullptr, d_out, BB*NQ, NQ, 3);
}